// Round 1
// 243.805 us; speedup vs baseline: 1.0140x; 1.0140x over previous
//
#include <hip/hip_runtime.h>

// CortexNetwork: aff + 0.9*exc - 0.9*inh, relu, broadcast over C.
// R2: 101us, 2.6 TB/s CU-ingress, occupancy-invariant -> per-CU L1-miss
//     concurrency (MSHR) limited on single-use data.
// R3: nontemporal weight loads -> phase1 now <61us (below the harness fill
//     dispatches in the profile).
// R4 (this round):
//   (a) all 16 lateral NT loads issued up-front (was 8-deep x 2 trips) ->
//       double the per-wave outstanding-miss depth; afferent FMAs overlap
//       the lateral miss latency.
//   (b) partials live in out[0..4*GG) instead of d_ws (phase2 reads its 4
//       partials before writing its 16 outputs per column -> race-free).
//       d_ws is never touched.
//   Grid stays GG*SPLIT=5184 blocks: fusing to 1296 blocks risks a ~15%
//   balance tail (5.06 blocks/CU at 4-resident) > phase2's ~3us.

constexpr int C   = 16;
constexpr int GX  = 36;
constexpr int GY  = 36;
constexpr int RF  = 24;
constexpr int IMG = 64;
constexpr int GG  = GX * GY;   // 1296
constexpr int RR  = RF * RF;   // 576
constexpr int RR4 = RR / 4;    // 144
constexpr int GG4 = GG / 4;    // 324
constexpr int RFQ = RF / 4;    // 6
constexpr int SPLIT = 4;
constexpr int CPB   = C / SPLIT;   // 4 channels per block

typedef float f4 __attribute__((ext_vector_type(4)));

__global__ __launch_bounds__(256)
void cortex_phase1(const float* __restrict__ x,
                   const float* __restrict__ prev,
                   const float* __restrict__ affW,
                   const float* __restrict__ exW,
                   const float* __restrict__ inW,
                   const int*   __restrict__ rx,
                   const int*   __restrict__ ry,
                   float* __restrict__ partial)
{
    const int bid   = blockIdx.x;
    const int ij    = bid % GG;
    const int split = bid / GG;
    const int cs    = split * CPB;
    const int i = ij / GY;
    const int j = ij - i * GY;
    const int t = threadIdx.x;

    const int rxi = rx[i];
    const int ryj = ry[j];

    // ---- Lateral loads FIRST: 16 nontemporal f4 loads in flight per thread
    //      (4 channels x {ex,in} x {k0=t, k1=t+256}) ----
    const int  k1  = t + 256;
    const bool k1v = (k1 < GG4);    // only t < 68 has a second chunk
    const f4 fz = {0.0f, 0.0f, 0.0f, 0.0f};

    f4 e0[CPB], h0[CPB], e1[CPB], h1[CPB];
    #pragma unroll
    for (int cc = 0; cc < CPB; ++cc) {
        const size_t base = ((size_t)(cs + cc) * GG + ij) * GG;
        const f4* ep = (const f4*)(exW + base);
        const f4* hp = (const f4*)(inW + base);
        e0[cc] = __builtin_nontemporal_load(ep + t);
        h0[cc] = __builtin_nontemporal_load(hp + t);
    }
    #pragma unroll
    for (int cc = 0; cc < CPB; ++cc) {
        const size_t base = ((size_t)(cs + cc) * GG + ij) * GG;
        const f4* ep = (const f4*)(exW + base);
        const f4* hp = (const f4*)(inW + base);
        if (k1v) {
            e1[cc] = __builtin_nontemporal_load(ep + k1);
            h1[cc] = __builtin_nontemporal_load(hp + k1);
        } else {
            e1[cc] = fz;
            h1[cc] = fz;
        }
    }

    float acc = 0.0f;

    // ---- Afferent: overlaps the outstanding lateral misses.
    //      4 channels x 144 f4 of affW (nontemporal); x via L1/L2 (reused). ----
    if (t < RR4) {
        const int u  = t / RFQ;
        const int v0 = 4 * (t - u * RFQ);
        f4 w[CPB];
        #pragma unroll
        for (int cc = 0; cc < CPB; ++cc) {
            const int c = cs + cc;
            w[cc] = __builtin_nontemporal_load(
                (const f4*)(affW + ((size_t)c * GG + ij) * RR) + t);
        }
        #pragma unroll
        for (int cc = 0; cc < CPB; ++cc) {
            const int c = cs + cc;
            const float* xp = x + ((c * IMG + rxi + u) * IMG + ryj + v0);
            acc = fmaf(w[cc].x, xp[0], acc);
            acc = fmaf(w[cc].y, xp[1], acc);
            acc = fmaf(w[cc].z, xp[2], acc);
            acc = fmaf(w[cc].w, xp[3], acc);
        }
    }

    // ---- Lateral arithmetic ----
    float lat = 0.0f;
    #pragma unroll
    for (int cc = 0; cc < CPB; ++cc) {
        const float d = (e0[cc].x + e0[cc].y + e0[cc].z + e0[cc].w)
                      + (e1[cc].x + e1[cc].y + e1[cc].z + e1[cc].w)
                      - (h0[cc].x + h0[cc].y + h0[cc].z + h0[cc].w)
                      - (h1[cc].x + h1[cc].y + h1[cc].z + h1[cc].w);
        lat = fmaf(prev[(cs + cc) * GG + ij], d, lat);
    }
    acc = fmaf(0.9f, lat, acc);

    // ---- Block reduction ----
    for (int off = 32; off > 0; off >>= 1)
        acc += __shfl_down(acc, off, 64);

    __shared__ float sred[4];
    const int wave = t >> 6;
    const int lane = t & 63;
    if (lane == 0) sred[wave] = acc;
    __syncthreads();
    if (t == 0)
        partial[split * GG + ij] = sred[0] + sred[1] + sred[2] + sred[3];
}

__global__ __launch_bounds__(256)
void cortex_phase2(const float* __restrict__ partial, float* __restrict__ out)
{
    const int ij = blockIdx.x * blockDim.x + threadIdx.x;
    if (ij < GG) {
        // partial aliases out[0..4*GG): read all 4 partials for this column
        // BEFORE writing any output (per-thread columns are disjoint).
        const float tot = partial[ij] + partial[GG + ij]
                        + partial[2 * GG + ij] + partial[3 * GG + ij];
        const float a = fmaxf(tot, 0.0f);
        #pragma unroll
        for (int c = 0; c < C; ++c)
            out[c * GG + ij] = a;
    }
}

extern "C" void kernel_launch(void* const* d_in, const int* in_sizes, int n_in,
                              void* d_out, int out_size, void* d_ws, size_t ws_size,
                              hipStream_t stream) {
    const float* x     = (const float*)d_in[0];
    const float* prev  = (const float*)d_in[1];
    const float* affW  = (const float*)d_in[2];
    const float* exW   = (const float*)d_in[3];
    const float* inW   = (const float*)d_in[4];
    const int*   rx    = (const int*)d_in[5];
    const int*   ry    = (const int*)d_in[6];
    float* out     = (float*)d_out;
    // Partials live in the first SPLIT*GG floats of out itself; d_ws unused.
    float* partial = out;

    cortex_phase1<<<GG * SPLIT, 256, 0, stream>>>(x, prev, affW, exW, inW, rx, ry, partial);
    cortex_phase2<<<(GG + 255) / 256, 256, 0, stream>>>(partial, out);
}